// Round 1
// baseline (676.779 us; speedup 1.0000x reference)
//
#include <hip/hip_runtime.h>

typedef unsigned short u16;
typedef short bf16x8 __attribute__((ext_vector_type(8)));
typedef float f32x4 __attribute__((ext_vector_type(4)));

#define NBATCH 8192

__device__ __forceinline__ f32x4 mfma16(bf16x8 a, bf16x8 b, f32x4 c) {
  return __builtin_amdgcn_mfma_f32_16x16x32_bf16(a, b, c, 0, 0, 0);
}
__device__ __forceinline__ u16 f2bf(float f) {
  unsigned int u = __float_as_uint(f);
  return (u16)((u + 0x7FFFu + ((u >> 16) & 1u)) >> 16);
}
__device__ __forceinline__ float sigm(float x) {
  return __builtin_amdgcn_rcpf(1.f + __builtin_amdgcn_exp2f(-1.44269504f * x));
}
__device__ __forceinline__ float tanh_(float x) {
  float t = __builtin_amdgcn_exp2f(2.88539008f * x);
  return 1.f - 2.f * __builtin_amdgcn_rcpf(t + 1.f);
}

// ------------------------- prep: fp32 -> bf16 weight copies -------------------------
__global__ void k_prep(const float* __restrict__ a, const float* __restrict__ b,
                       const float* __restrict__ c,
                       u16* __restrict__ oa, u16* __restrict__ ob, u16* __restrict__ oc) {
  int i = blockIdx.x * 256 + threadIdx.x;
  if (i < 49152) { oa[i] = f2bf(a[i]); ob[i] = f2bf(b[i]); oc[i] = f2bf(c[i]); }
}

// ------------------------- fused 2-layer GRU recurrence -------------------------
// 256 blocks x 512 threads (8 waves). 32 samples/block, all 64 steps, both layers.
// LDS: W_hh0 bf16 swizzled (96K) | h0 f32 (16.5K) | h1 f32 (16.5K) | h0 bf16 swz (8K)
//      | h1 bf16 swz (8K) | x_t staging (1K)
#define WHH0_OFF 0
#define H0F_OFF  98304
#define H1F_OFF  115200
#define H0B_OFF  132096
#define H1B_OFF  140288
#define XT_OFF   148480
#define GRU_LDS  149504

__global__ __launch_bounds__(512, 2)
void k_gru(const float* __restrict__ x,
           const float* __restrict__ wih0, const float* __restrict__ bih0,
           const float* __restrict__ bhh0,
           const u16* __restrict__ whh0b, const u16* __restrict__ wih1b,
           const u16* __restrict__ whh1b,
           const float* __restrict__ bih1, const float* __restrict__ bhh1,
           float* __restrict__ hraw) {
  extern __shared__ char sm[];
  const int tid = threadIdx.x;
  const int wid = tid >> 6;
  const int lane = tid & 63;
  const int lq = lane >> 4;       // k-chunk index within MFMA
  const int ul = lane & 15;       // column within N-tile == A-row within M-tile
  const int u  = wid * 16 + ul;   // hidden unit owned by this lane (0..127)
  const int n0 = blockIdx.x * 32;
  const int sx = (ul & 7) << 4;   // swizzle term shared by A reads (s&7==ul&7)

  // stage W_hh0 into LDS, 16B chunks, XOR-swizzled (row&7)<<4
  for (int idx = tid; idx < 384 * 16; idx += 512) {
    int g = idx >> 4, cb = idx & 15;
    uint4 v = *(const uint4*)(whh0b + g * 128 + cb * 8);
    *(uint4*)(sm + WHH0_OFF + g * 256 + ((cb * 16) ^ ((g & 7) << 4))) = v;
  }
  // zero h state buffers (h0f,h1f,h0b,h1b contiguous = 50176B)
  for (int idx = tid; idx < 12544; idx += 512)
    *(float*)(sm + H0F_OFF + idx * 4) = 0.f;
  if (tid < 256) *(float*)(sm + XT_OFF + tid * 4) = 0.f;

  // per-wave register-resident B-fragments for W_ih1, W_hh1
  bf16x8 wih1f[3][4], whh1f[3][4];
#pragma unroll
  for (int i = 0; i < 3; ++i) {
    int g = (wid + 8 * i) * 16 + ul;     // == u + 128*i
#pragma unroll
    for (int ki = 0; ki < 4; ++ki) {
      wih1f[i][ki] = *(const bf16x8*)(wih1b + g * 128 + ki * 32 + lq * 8);
      whh1f[i][ki] = *(const bf16x8*)(whh1b + g * 128 + ki * 32 + lq * 8);
    }
  }
  // per-lane small weights/biases (gates r,z,n for unit u)
  float wi0[3][6], bi0v[3], bh0v[3], bi1v[3], bh1v[3];
#pragma unroll
  for (int i = 0; i < 3; ++i) {
    int g = u + 128 * i;
#pragma unroll
    for (int d = 0; d < 6; ++d) wi0[i][d] = wih0[g * 6 + d];
    bi0v[i] = bih0[g]; bh0v[i] = bhh0[g];
    bi1v[i] = bih1[g]; bh1v[i] = bhh1[g];
  }

  // x prefetch: 192 threads each own one (sample, feature) pair
  const int xm = tid / 6, xd = tid - 6 * xm;
  const bool xact = tid < 192;
  const float* gx = x + (size_t)(n0 + xm) * 384 + xd * 64;
  float xv = xact ? gx[0] : 0.f;

  __syncthreads();

  float* h0f = (float*)(sm + H0F_OFF);
  float* h1f = (float*)(sm + H1F_OFF);

  for (int t = 0; t < 64; ++t) {
    if (xact) *(float*)(sm + XT_OFF + (xm * 8 + xd) * 4) = xv;

    // ---- phase 1: gh0 = h0_{t-1} @ W_hh0^T (MFMA) ----
    f32x4 acc0[2][3];
#pragma unroll
    for (int mt = 0; mt < 2; ++mt)
#pragma unroll
      for (int i = 0; i < 3; ++i) acc0[mt][i] = (f32x4){0.f, 0.f, 0.f, 0.f};
#pragma unroll
    for (int ki = 0; ki < 4; ++ki) {
      int ko = ki * 64 + lq * 16;
      bf16x8 a0 = *(bf16x8*)(sm + H0B_OFF + ul * 256 + (ko ^ sx));
      bf16x8 a1 = *(bf16x8*)(sm + H0B_OFF + (16 + ul) * 256 + (ko ^ sx));
#pragma unroll
      for (int i = 0; i < 3; ++i) {
        int g = u + 128 * i;
        bf16x8 bw = *(bf16x8*)(sm + WHH0_OFF + g * 256 + (ko ^ ((g & 7) << 4)));
        acc0[0][i] = mfma16(a0, bw, acc0[0][i]);
        acc0[1][i] = mfma16(a1, bw, acc0[1][i]);
      }
    }
    __syncthreads();  // B1: frag reads done -> safe to update h0

    // ---- layer-0 elementwise (gi0 from x in fp32) ----
#pragma unroll
    for (int mt = 0; mt < 2; ++mt) {
#pragma unroll
      for (int r = 0; r < 4; ++r) {
        int m = mt * 16 + lq * 4 + r;
        const float* xr = (const float*)(sm + XT_OFF + m * 32);
        float gi[3];
#pragma unroll
        for (int i = 0; i < 3; ++i) {
          float s = bi0v[i];
#pragma unroll
          for (int d = 0; d < 6; ++d) s += wi0[i][d] * xr[d];
          gi[i] = s;
        }
        float hr = acc0[mt][0][r] + bh0v[0];
        float hz = acc0[mt][1][r] + bh0v[1];
        float hn = acc0[mt][2][r] + bh0v[2];
        float rr = sigm(gi[0] + hr);
        float zz = sigm(gi[1] + hz);
        float nn = tanh_(gi[2] + rr * hn);
        float hold = h0f[m * 132 + u];
        float hnew = (1.f - zz) * nn + zz * hold;
        h0f[m * 132 + u] = hnew;
        *(u16*)(sm + H0B_OFF + m * 256 + ((u * 2) ^ ((m & 7) << 4))) = f2bf(hnew);
      }
    }
    __syncthreads();  // B2: h0_t visible

    if (xact && t < 63) xv = gx[t + 1];  // prefetch next x slice

    // ---- phase 5: gi1 = h0_t @ W_ih1^T ; gh1 = h1_{t-1} @ W_hh1^T ----
    f32x4 accA[2][3], accB[2][3];
#pragma unroll
    for (int mt = 0; mt < 2; ++mt)
#pragma unroll
      for (int i = 0; i < 3; ++i) {
        accA[mt][i] = (f32x4){0.f, 0.f, 0.f, 0.f};
        accB[mt][i] = (f32x4){0.f, 0.f, 0.f, 0.f};
      }
#pragma unroll
    for (int ki = 0; ki < 4; ++ki) {
      int ko = ki * 64 + lq * 16;
      bf16x8 p0 = *(bf16x8*)(sm + H0B_OFF + ul * 256 + (ko ^ sx));
      bf16x8 p1 = *(bf16x8*)(sm + H0B_OFF + (16 + ul) * 256 + (ko ^ sx));
      bf16x8 q0 = *(bf16x8*)(sm + H1B_OFF + ul * 256 + (ko ^ sx));
      bf16x8 q1 = *(bf16x8*)(sm + H1B_OFF + (16 + ul) * 256 + (ko ^ sx));
#pragma unroll
      for (int i = 0; i < 3; ++i) {
        accA[0][i] = mfma16(p0, wih1f[i][ki], accA[0][i]);
        accA[1][i] = mfma16(p1, wih1f[i][ki], accA[1][i]);
        accB[0][i] = mfma16(q0, whh1f[i][ki], accB[0][i]);
        accB[1][i] = mfma16(q1, whh1f[i][ki], accB[1][i]);
      }
    }
    __syncthreads();  // B3

    // ---- layer-1 elementwise ----
#pragma unroll
    for (int mt = 0; mt < 2; ++mt) {
#pragma unroll
      for (int r = 0; r < 4; ++r) {
        int m = mt * 16 + lq * 4 + r;
        float ir = accA[mt][0][r] + bi1v[0];
        float iz = accA[mt][1][r] + bi1v[1];
        float in_ = accA[mt][2][r] + bi1v[2];
        float hr = accB[mt][0][r] + bh1v[0];
        float hz = accB[mt][1][r] + bh1v[1];
        float hn = accB[mt][2][r] + bh1v[2];
        float rr = sigm(ir + hr);
        float zz = sigm(iz + hz);
        float nn = tanh_(in_ + rr * hn);
        float hold = h1f[m * 132 + u];
        float hnew = (1.f - zz) * nn + zz * hold;
        h1f[m * 132 + u] = hnew;
        *(u16*)(sm + H1B_OFF + m * 256 + ((u * 2) ^ ((m & 7) << 4))) = f2bf(hnew);
      }
    }
    __syncthreads();  // B4
  }

  for (int idx = tid; idx < 4096; idx += 512) {
    int m = idx >> 7, f = idx & 127;
    hraw[(size_t)(n0 + m) * 128 + f] = h1f[m * 132 + f];
  }
}

// ------------------------- BN1 stats (per feature over batch) -------------------------
__global__ void k_bn1(const float* __restrict__ hraw, float* __restrict__ mu1,
                      float* __restrict__ rs1) {
  __shared__ float rs[256], rq[256];
  int f = blockIdx.x, tid = threadIdx.x;
  float s = 0.f, q = 0.f;
  for (int n = tid; n < NBATCH; n += 256) {
    float v = hraw[(size_t)n * 128 + f];
    s += v; q += v * v;
  }
  rs[tid] = s; rq[tid] = q; __syncthreads();
  for (int off = 128; off; off >>= 1) {
    if (tid < off) { rs[tid] += rs[tid + off]; rq[tid] += rq[tid + off]; }
    __syncthreads();
  }
  if (!tid) {
    float mu = rs[0] / 8192.f;
    float var = rq[0] / 8192.f - mu * mu;
    mu1[f] = mu; rs1[f] = rsqrtf(var + 1e-5f);
  }
}

// ------------------------- BN1 apply + row means + Gram/mh partials -------------------------
__global__ void k_attp(const float* __restrict__ hraw, const float* __restrict__ mu1,
                       const float* __restrict__ rs1, const float* __restrict__ g1,
                       const float* __restrict__ b1, float* __restrict__ hidden,
                       float* __restrict__ mvec, float* __restrict__ gpart,
                       float* __restrict__ mhpart) {
  __shared__ float hid[64][128];
  __shared__ float mld[64];
  int tid = threadIdx.x, blk = blockIdx.x, n0 = blk * 64;
  for (int idx = tid; idx < 64 * 128; idx += 256) {
    int n = idx >> 7, f = idx & 127;
    float v = (hraw[(size_t)(n0 + n) * 128 + f] - mu1[f]) * rs1[f] * g1[f] + b1[f];
    hid[n][f] = v;
    hidden[(size_t)(n0 + n) * 128 + f] = v;
  }
  __syncthreads();
  if (tid < 64) {
    float s = 0.f;
    for (int f = 0; f < 128; ++f) s += hid[tid][f];
    s *= (1.f / 128.f);
    mld[tid] = s; mvec[n0 + tid] = s;
  }
  __syncthreads();
  int i = tid >> 1, j0 = (tid & 1) * 64;
  float acc[64];
#pragma unroll
  for (int j = 0; j < 64; ++j) acc[j] = 0.f;
  for (int n = 0; n < 64; ++n) {
    float a = hid[n][i];
#pragma unroll
    for (int j = 0; j < 64; ++j) acc[j] += a * hid[n][j0 + j];
  }
#pragma unroll
  for (int j = 0; j < 64; ++j) gpart[(size_t)blk * 16384 + i * 128 + j0 + j] = acc[j];
  if (tid < 128) {
    float s = 0.f;
    for (int n = 0; n < 64; ++n) s += mld[n] * hid[n][tid];
    mhpart[blk * 128 + tid] = s;
  }
}

// ------------------------- reduce Gram/mh partials -------------------------
__global__ void k_attfa(const float* __restrict__ gpart, const float* __restrict__ mhpart,
                        float* __restrict__ gfull, float* __restrict__ mhfull) {
  int idx = blockIdx.x * 256 + threadIdx.x;  // 0..16383
  float s = 0.f;
  for (int b = 0; b < 128; ++b) s += gpart[(size_t)b * 16384 + idx];
  gfull[idx] = s;
  if (blockIdx.x == 0 && threadIdx.x < 128) {
    float t = 0.f;
    for (int b = 0; b < 128; ++b) t += mhpart[b * 128 + threadIdx.x];
    mhfull[threadIdx.x] = t;
  }
}

// ------------------------- M2 = (G/H) @ fc_w^T ; u = mh @ fc_w^T -------------------------
__global__ void k_attfb(const float* __restrict__ gfull, const float* __restrict__ mhfull,
                        const float* __restrict__ fcw, float* __restrict__ m2,
                        float* __restrict__ uvec) {
  extern __shared__ char smf[];
  float* gl = (float*)smf;       // 16384
  float* fwT = gl + 16384;       // 16384 (fc_w transposed: [f][j])
  float* mh = fwT + 16384;       // 128
  int tid = threadIdx.x;
  for (int idx = tid; idx < 16384; idx += 256) {
    gl[idx] = gfull[idx];
    int jj = idx >> 7, f = idx & 127;
    fwT[f * 128 + jj] = fcw[idx];
  }
  if (tid < 128) mh[tid] = mhfull[tid];
  __syncthreads();
  for (int idx = tid; idx < 16384; idx += 256) {
    int k = idx >> 7, j = idx & 127;
    float s = 0.f;
    for (int f = 0; f < 128; ++f) s += gl[k * 128 + f] * fwT[f * 128 + j];
    m2[idx] = s * (1.f / 128.f);
  }
  if (tid < 128) {
    float s = 0.f;
    for (int f = 0; f < 128; ++f) s += mh[f] * fwT[f * 128 + tid];
    uvec[tid] = s;
  }
}

// ------------------------- out2 = hidden@M2 - m*u + fc_b ; BN2 partials -------------------------
__global__ void k_out2(const float* __restrict__ hidden, const float* __restrict__ mvec,
                       const float* __restrict__ m2g, const float* __restrict__ uvec,
                       const float* __restrict__ fcb, float* __restrict__ out2,
                       float* __restrict__ bn2p) {
  extern __shared__ char smo[];
  float* m2l = (float*)smo;       // 16384
  float* hl = m2l + 16384;        // 4096
  float* ml = hl + 4096;          // 32
  float* red = ml + 32;           // 512
  int tid = threadIdx.x, blk = blockIdx.x, n0 = blk * 32;
  for (int idx = tid; idx < 16384; idx += 256) m2l[idx] = m2g[idx];
  for (int idx = tid; idx < 4096; idx += 256) hl[idx] = hidden[(size_t)n0 * 128 + idx];
  if (tid < 32) ml[tid] = mvec[n0 + tid];
  __syncthreads();
  int j = tid & 127, rg = tid >> 7;
  float uj = uvec[j], bj = fcb[j];
  float s1 = 0.f, s2 = 0.f;
  for (int q = 0; q < 16; ++q) {
    int nl = rg * 16 + q;
    float s = bj - ml[nl] * uj;
    const float* hr = hl + nl * 128;
#pragma unroll 8
    for (int k = 0; k < 128; ++k) s += hr[k] * m2l[k * 128 + j];
    out2[(size_t)(n0 + nl) * 128 + j] = s;
    s1 += s; s2 += s * s;
  }
  red[tid] = s1; red[256 + tid] = s2;
  __syncthreads();
  if (tid < 128) {
    bn2p[blk * 256 + tid] = red[tid] + red[128 + tid];
    bn2p[blk * 256 + 128 + tid] = red[256 + tid] + red[384 + tid];
  }
}

// ------------------------- BN2 stats -------------------------
__global__ void k_bn2(const float* __restrict__ bn2p, float* __restrict__ mu2,
                      float* __restrict__ rs2) {
  int j = threadIdx.x;  // 128
  float s = 0.f, q = 0.f;
  for (int b = 0; b < 256; ++b) {
    s += bn2p[b * 256 + j];
    q += bn2p[b * 256 + 128 + j];
  }
  float mu = s / 8192.f, var = q / 8192.f - mu * mu;
  mu2[j] = mu; rs2[j] = rsqrtf(var + 1e-5f);
}

// ------------------------- BN2 apply + leaky-relu + final GEMV -------------------------
__global__ void k_fin(const float* __restrict__ out2, const float* __restrict__ mu2,
                      const float* __restrict__ rs2, const float* __restrict__ g2,
                      const float* __restrict__ b2, const float* __restrict__ fcow,
                      const float* __restrict__ fcob, float* __restrict__ y) {
  int tid = threadIdx.x, lane = tid & 63, w = tid >> 6;
  int n = blockIdx.x * 4 + w;
  float s = 0.f;
#pragma unroll
  for (int h = 0; h < 2; ++h) {
    int j = lane + h * 64;
    float v = (out2[(size_t)n * 128 + j] - mu2[j]) * rs2[j] * g2[j] + b2[j];
    v = fmaxf(v, 0.01f * v);
    s += v * fcow[j];
  }
  for (int off = 32; off; off >>= 1) s += __shfl_down(s, off);
  if (!lane) y[n] = s + fcob[0];
}

// ------------------------- launch -------------------------
extern "C" void kernel_launch(void* const* d_in, const int* in_sizes, int n_in,
                              void* d_out, int out_size, void* d_ws, size_t ws_size,
                              hipStream_t stream) {
  const float* x    = (const float*)d_in[0];
  const float* wih0 = (const float*)d_in[1];
  const float* whh0 = (const float*)d_in[2];
  const float* bih0 = (const float*)d_in[3];
  const float* bhh0 = (const float*)d_in[4];
  const float* wih1 = (const float*)d_in[5];
  const float* whh1 = (const float*)d_in[6];
  const float* bih1 = (const float*)d_in[7];
  const float* bhh1 = (const float*)d_in[8];
  const float* g1   = (const float*)d_in[9];
  const float* b1   = (const float*)d_in[10];
  const float* fcw  = (const float*)d_in[11];
  const float* fcb  = (const float*)d_in[12];
  const float* g2   = (const float*)d_in[13];
  const float* b2   = (const float*)d_in[14];
  const float* fcow = (const float*)d_in[15];
  const float* fcob = (const float*)d_in[16];

  char* ws = (char*)d_ws;
  u16*   whh0b  = (u16*)(ws + 0);
  u16*   wih1b  = (u16*)(ws + 98304);
  u16*   whh1b  = (u16*)(ws + 196608);
  float* hraw   = (float*)(ws + 294912);
  float* hidden = (float*)(ws + 4489216);
  float* mvec   = (float*)(ws + 8683520);
  float* mu1    = (float*)(ws + 8716288);
  float* rs1    = (float*)(ws + 8716800);
  float* gpart  = (float*)(ws + 8717312);
  float* mhpart = (float*)(ws + 17105920);
  float* m2     = (float*)(ws + 17171456);
  float* uvec   = (float*)(ws + 17236992);
  float* out2   = (float*)(ws + 17237504);
  float* bn2p   = (float*)(ws + 21431808);
  float* mu2    = (float*)(ws + 21693952);
  float* rs2    = (float*)(ws + 21694464);
  float* gfull  = (float*)(ws + 21694976);
  float* mhfull = (float*)(ws + 21760512);

  (void)hipFuncSetAttribute((const void*)k_gru,
                            hipFuncAttributeMaxDynamicSharedMemorySize, GRU_LDS);
  (void)hipFuncSetAttribute((const void*)k_attfb,
                            hipFuncAttributeMaxDynamicSharedMemorySize, 132096);
  (void)hipFuncSetAttribute((const void*)k_out2,
                            hipFuncAttributeMaxDynamicSharedMemorySize, 84096);

  k_prep<<<192, 256, 0, stream>>>(whh0, wih1, whh1, whh0b, wih1b, whh1b);
  k_gru<<<256, 512, GRU_LDS, stream>>>(x, wih0, bih0, bhh0, whh0b, wih1b, whh1b,
                                       bih1, bhh1, hraw);
  k_bn1<<<128, 256, 0, stream>>>(hraw, mu1, rs1);
  k_attp<<<128, 256, 0, stream>>>(hraw, mu1, rs1, g1, b1, hidden, mvec, gpart, mhpart);
  k_attfa<<<64, 256, 0, stream>>>(gpart, mhpart, gfull, mhfull);
  k_attfb<<<1, 256, 132096, stream>>>(gfull, mhfull, fcw, m2, uvec);
  k_out2<<<256, 256, 84096, stream>>>(hidden, mvec, m2, uvec, fcb, out2, bn2p);
  k_bn2<<<1, 128, 0, stream>>>(bn2p, mu2, rs2);
  k_fin<<<2048, 256, 0, stream>>>(out2, mu2, rs2, g2, b2, fcow, fcob, (float*)d_out);
}

// Round 2
// 380.424 us; speedup vs baseline: 1.7790x; 1.7790x over previous
//
#include <hip/hip_runtime.h>

typedef unsigned short u16;
typedef short bf16x8 __attribute__((ext_vector_type(8)));
typedef float f32x4 __attribute__((ext_vector_type(4)));

#define NBATCH 8192

__device__ __forceinline__ f32x4 mfma16(bf16x8 a, bf16x8 b, f32x4 c) {
  return __builtin_amdgcn_mfma_f32_16x16x32_bf16(a, b, c, 0, 0, 0);
}
__device__ __forceinline__ u16 f2bf(float f) {
  unsigned int u = __float_as_uint(f);
  return (u16)((u + 0x7FFFu + ((u >> 16) & 1u)) >> 16);
}
__device__ __forceinline__ float sigm(float x) {
  return __builtin_amdgcn_rcpf(1.f + __builtin_amdgcn_exp2f(-1.44269504f * x));
}
__device__ __forceinline__ float tanh_(float x) {
  float t = __builtin_amdgcn_exp2f(2.88539008f * x);
  return 1.f - 2.f * __builtin_amdgcn_rcpf(t + 1.f);
}

// ------------------------- prep: fp32 -> bf16 weight copies -------------------------
__global__ void k_prep(const float* __restrict__ a, const float* __restrict__ b,
                       const float* __restrict__ c,
                       u16* __restrict__ oa, u16* __restrict__ ob, u16* __restrict__ oc) {
  int i = blockIdx.x * 256 + threadIdx.x;
  if (i < 49152) { oa[i] = f2bf(a[i]); ob[i] = f2bf(b[i]); oc[i] = f2bf(c[i]); }
}

// ------------------------- fused 2-layer GRU recurrence -------------------------
// 256 blocks x 512 threads (8 waves). 32 samples/block, all 64 steps, both layers.
#define WHH0_OFF 0
#define H0F_OFF  98304
#define H1F_OFF  115200
#define H0B_OFF  132096
#define H1B_OFF  140288
#define XT_OFF   148480
#define GRU_LDS  149504

__global__ __launch_bounds__(512, 2)
void k_gru(const float* __restrict__ x,
           const float* __restrict__ wih0, const float* __restrict__ bih0,
           const float* __restrict__ bhh0,
           const u16* __restrict__ whh0b, const u16* __restrict__ wih1b,
           const u16* __restrict__ whh1b,
           const float* __restrict__ bih1, const float* __restrict__ bhh1,
           float* __restrict__ hraw) {
  extern __shared__ char sm[];
  const int tid = threadIdx.x;
  const int wid = tid >> 6;
  const int lane = tid & 63;
  const int lq = lane >> 4;       // k-chunk index within MFMA
  const int ul = lane & 15;       // column within N-tile == A-row within M-tile
  const int u  = wid * 16 + ul;   // hidden unit owned by this lane (0..127)
  const int n0 = blockIdx.x * 32;
  const int sx = (ul & 7) << 4;   // swizzle term shared by A reads (s&7==ul&7)

  // stage W_hh0 into LDS, 16B chunks, XOR-swizzled (row&7)<<4
  for (int idx = tid; idx < 384 * 16; idx += 512) {
    int g = idx >> 4, cb = idx & 15;
    uint4 v = *(const uint4*)(whh0b + g * 128 + cb * 8);
    *(uint4*)(sm + WHH0_OFF + g * 256 + ((cb * 16) ^ ((g & 7) << 4))) = v;
  }
  // zero h state buffers (h0f,h1f,h0b,h1b contiguous = 50176B)
  for (int idx = tid; idx < 12544; idx += 512)
    *(float*)(sm + H0F_OFF + idx * 4) = 0.f;
  if (tid < 256) *(float*)(sm + XT_OFF + tid * 4) = 0.f;

  // per-wave register-resident B-fragments for W_ih1, W_hh1
  bf16x8 wih1f[3][4], whh1f[3][4];
#pragma unroll
  for (int i = 0; i < 3; ++i) {
    int g = (wid + 8 * i) * 16 + ul;     // == u + 128*i
#pragma unroll
    for (int ki = 0; ki < 4; ++ki) {
      wih1f[i][ki] = *(const bf16x8*)(wih1b + g * 128 + ki * 32 + lq * 8);
      whh1f[i][ki] = *(const bf16x8*)(whh1b + g * 128 + ki * 32 + lq * 8);
    }
  }
  // per-lane small weights/biases (gates r,z,n for unit u)
  float wi0[3][6], bi0v[3], bh0v[3], bi1v[3], bh1v[3];
#pragma unroll
  for (int i = 0; i < 3; ++i) {
    int g = u + 128 * i;
#pragma unroll
    for (int d = 0; d < 6; ++d) wi0[i][d] = wih0[g * 6 + d];
    bi0v[i] = bih0[g]; bh0v[i] = bhh0[g];
    bi1v[i] = bih1[g]; bh1v[i] = bhh1[g];
  }

  // x prefetch: 192 threads each own one (sample, feature) pair
  const int xm = tid / 6, xd = tid - 6 * xm;
  const bool xact = tid < 192;
  const float* gx = x + (size_t)(n0 + xm) * 384 + xd * 64;
  float xv = xact ? gx[0] : 0.f;

  __syncthreads();

  float* h0f = (float*)(sm + H0F_OFF);
  float* h1f = (float*)(sm + H1F_OFF);

  for (int t = 0; t < 64; ++t) {
    if (xact) *(float*)(sm + XT_OFF + (xm * 8 + xd) * 4) = xv;

    // ---- phase 1: gh0 = h0_{t-1} @ W_hh0^T (MFMA) ----
    f32x4 acc0[2][3];
#pragma unroll
    for (int mt = 0; mt < 2; ++mt)
#pragma unroll
      for (int i = 0; i < 3; ++i) acc0[mt][i] = (f32x4){0.f, 0.f, 0.f, 0.f};
#pragma unroll
    for (int ki = 0; ki < 4; ++ki) {
      int ko = ki * 64 + lq * 16;
      bf16x8 a0 = *(bf16x8*)(sm + H0B_OFF + ul * 256 + (ko ^ sx));
      bf16x8 a1 = *(bf16x8*)(sm + H0B_OFF + (16 + ul) * 256 + (ko ^ sx));
#pragma unroll
      for (int i = 0; i < 3; ++i) {
        int g = u + 128 * i;
        bf16x8 bw = *(bf16x8*)(sm + WHH0_OFF + g * 256 + (ko ^ ((g & 7) << 4)));
        acc0[0][i] = mfma16(a0, bw, acc0[0][i]);
        acc0[1][i] = mfma16(a1, bw, acc0[1][i]);
      }
    }
    __syncthreads();  // B1: frag reads done -> safe to update h0

    // ---- layer-0 elementwise (gi0 from x in fp32) ----
#pragma unroll
    for (int mt = 0; mt < 2; ++mt) {
#pragma unroll
      for (int r = 0; r < 4; ++r) {
        int m = mt * 16 + lq * 4 + r;
        const float* xr = (const float*)(sm + XT_OFF + m * 32);
        float gi[3];
#pragma unroll
        for (int i = 0; i < 3; ++i) {
          float s = bi0v[i];
#pragma unroll
          for (int d = 0; d < 6; ++d) s += wi0[i][d] * xr[d];
          gi[i] = s;
        }
        float hr = acc0[mt][0][r] + bh0v[0];
        float hz = acc0[mt][1][r] + bh0v[1];
        float hn = acc0[mt][2][r] + bh0v[2];
        float rr = sigm(gi[0] + hr);
        float zz = sigm(gi[1] + hz);
        float nn = tanh_(gi[2] + rr * hn);
        float hold = h0f[m * 132 + u];
        float hnew = (1.f - zz) * nn + zz * hold;
        h0f[m * 132 + u] = hnew;
        *(u16*)(sm + H0B_OFF + m * 256 + ((u * 2) ^ ((m & 7) << 4))) = f2bf(hnew);
      }
    }
    __syncthreads();  // B2: h0_t visible

    if (xact && t < 63) xv = gx[t + 1];  // prefetch next x slice

    // ---- phase 5: gi1 = h0_t @ W_ih1^T ; gh1 = h1_{t-1} @ W_hh1^T ----
    f32x4 accA[2][3], accB[2][3];
#pragma unroll
    for (int mt = 0; mt < 2; ++mt)
#pragma unroll
      for (int i = 0; i < 3; ++i) {
        accA[mt][i] = (f32x4){0.f, 0.f, 0.f, 0.f};
        accB[mt][i] = (f32x4){0.f, 0.f, 0.f, 0.f};
      }
#pragma unroll
    for (int ki = 0; ki < 4; ++ki) {
      int ko = ki * 64 + lq * 16;
      bf16x8 p0 = *(bf16x8*)(sm + H0B_OFF + ul * 256 + (ko ^ sx));
      bf16x8 p1 = *(bf16x8*)(sm + H0B_OFF + (16 + ul) * 256 + (ko ^ sx));
      bf16x8 q0 = *(bf16x8*)(sm + H1B_OFF + ul * 256 + (ko ^ sx));
      bf16x8 q1 = *(bf16x8*)(sm + H1B_OFF + (16 + ul) * 256 + (ko ^ sx));
#pragma unroll
      for (int i = 0; i < 3; ++i) {
        accA[0][i] = mfma16(p0, wih1f[i][ki], accA[0][i]);
        accA[1][i] = mfma16(p1, wih1f[i][ki], accA[1][i]);
        accB[0][i] = mfma16(q0, whh1f[i][ki], accB[0][i]);
        accB[1][i] = mfma16(q1, whh1f[i][ki], accB[1][i]);
      }
    }
    __syncthreads();  // B3

    // ---- layer-1 elementwise ----
#pragma unroll
    for (int mt = 0; mt < 2; ++mt) {
#pragma unroll
      for (int r = 0; r < 4; ++r) {
        int m = mt * 16 + lq * 4 + r;
        float ir = accA[mt][0][r] + bi1v[0];
        float iz = accA[mt][1][r] + bi1v[1];
        float in_ = accA[mt][2][r] + bi1v[2];
        float hr = accB[mt][0][r] + bh1v[0];
        float hz = accB[mt][1][r] + bh1v[1];
        float hn = accB[mt][2][r] + bh1v[2];
        float rr = sigm(ir + hr);
        float zz = sigm(iz + hz);
        float nn = tanh_(in_ + rr * hn);
        float hold = h1f[m * 132 + u];
        float hnew = (1.f - zz) * nn + zz * hold;
        h1f[m * 132 + u] = hnew;
        *(u16*)(sm + H1B_OFF + m * 256 + ((u * 2) ^ ((m & 7) << 4))) = f2bf(hnew);
      }
    }
    __syncthreads();  // B4
  }

  for (int idx = tid; idx < 4096; idx += 512) {
    int m = idx >> 7, f = idx & 127;
    hraw[(size_t)(n0 + m) * 128 + f] = h1f[m * 132 + f];
  }
}

// ------------------------- BN1 partials (coalesced) -------------------------
// 128 blocks x 256 threads; block b covers samples [b*64, b*64+64)
__global__ void k_bn1p(const float* __restrict__ hraw, float* __restrict__ p) {
  __shared__ float s0[256], s1[256];
  int tid = threadIdx.x, b = blockIdx.x;
  int f = tid & 127, r = tid >> 7;
  float s = 0.f, q = 0.f;
  for (int n = b * 64 + r; n < b * 64 + 64; n += 2) {
    float v = hraw[(size_t)n * 128 + f];
    s += v; q += v * v;
  }
  s0[tid] = s; s1[tid] = q;
  __syncthreads();
  if (tid < 128) {
    p[b * 256 + tid] = s0[tid] + s0[tid + 128];
    p[b * 256 + 128 + tid] = s1[tid] + s1[tid + 128];
  }
}

__global__ void k_bn1r(const float* __restrict__ p, float* __restrict__ mu1,
                       float* __restrict__ rs1) {
  int f = threadIdx.x;  // 128
  float s = 0.f, q = 0.f;
  for (int b = 0; b < 128; ++b) { s += p[b * 256 + f]; q += p[b * 256 + 128 + f]; }
  float mu = s / 8192.f, var = q / 8192.f - mu * mu;
  mu1[f] = mu; rs1[f] = rsqrtf(var + 1e-5f);
}

// ------------------------- BN1 apply + row means + Gram/mh partials -------------------------
__global__ void k_attp(const float* __restrict__ hraw, const float* __restrict__ mu1,
                       const float* __restrict__ rs1, const float* __restrict__ g1,
                       const float* __restrict__ b1, float* __restrict__ hidden,
                       float* __restrict__ mvec, float* __restrict__ gpart,
                       float* __restrict__ mhpart) {
  __shared__ float hid[64][128];
  __shared__ float mld[64];
  int tid = threadIdx.x, blk = blockIdx.x, n0 = blk * 64;
  for (int idx = tid; idx < 64 * 128; idx += 256) {
    int n = idx >> 7, f = idx & 127;
    float v = (hraw[(size_t)(n0 + n) * 128 + f] - mu1[f]) * rs1[f] * g1[f] + b1[f];
    hid[n][f] = v;
    hidden[(size_t)(n0 + n) * 128 + f] = v;
  }
  __syncthreads();
  if (tid < 64) {
    float s = 0.f;
    for (int f = 0; f < 128; ++f) s += hid[tid][f];
    s *= (1.f / 128.f);
    mld[tid] = s; mvec[n0 + tid] = s;
  }
  __syncthreads();
  int i = tid >> 1, j0 = (tid & 1) * 64;
  float acc[64];
#pragma unroll
  for (int j = 0; j < 64; ++j) acc[j] = 0.f;
  for (int n = 0; n < 64; ++n) {
    float a = hid[n][i];
#pragma unroll
    for (int j = 0; j < 64; ++j) acc[j] += a * hid[n][j0 + j];
  }
#pragma unroll
  for (int j = 0; j < 64; ++j) gpart[(size_t)blk * 16384 + i * 128 + j0 + j] = acc[j];
  if (tid < 128) {
    float s = 0.f;
    for (int n = 0; n < 64; ++n) s += mld[n] * hid[n][tid];
    mhpart[blk * 128 + tid] = s;
  }
}

// ------------------------- reduce Gram/mh partials -------------------------
__global__ void k_attfa(const float* __restrict__ gpart, const float* __restrict__ mhpart,
                        float* __restrict__ gfull, float* __restrict__ mhfull) {
  int idx = blockIdx.x * 256 + threadIdx.x;  // 0..16383
  float s = 0.f;
  for (int b = 0; b < 128; ++b) s += gpart[(size_t)b * 16384 + idx];
  gfull[idx] = s;
  if (blockIdx.x == 0 && threadIdx.x < 128) {
    float t = 0.f;
    for (int b = 0; b < 128; ++b) t += mhpart[b * 128 + threadIdx.x];
    mhfull[threadIdx.x] = t;
  }
}

// ------------------------- M2 = (G/H) @ fc_w^T ; u = mh @ fc_w^T -------------------------
// 128 blocks x 128 threads, one output per thread. Contraction is along the
// contiguous axis of BOTH operands (G row-major [k][f], fcw row-major [j][f]).
__global__ void k_attfb(const float* __restrict__ gfull, const float* __restrict__ mhfull,
                        const float* __restrict__ fcw, float* __restrict__ m2,
                        float* __restrict__ uvec) {
  int idx = blockIdx.x * 128 + threadIdx.x;
  int k = idx >> 7, j = idx & 127;
  const float4* ga = (const float4*)(gfull + k * 128);
  const float4* fb = (const float4*)(fcw + j * 128);
  float a0 = 0.f, a1 = 0.f, a2 = 0.f, a3 = 0.f;
#pragma unroll 8
  for (int f = 0; f < 32; ++f) {
    float4 a = ga[f], b = fb[f];
    a0 += a.x * b.x; a1 += a.y * b.y; a2 += a.z * b.z; a3 += a.w * b.w;
  }
  m2[idx] = (a0 + a1 + a2 + a3) * (1.f / 128.f);
  if (idx < 128) {
    float s = 0.f;
    const float* fr = fcw + idx * 128;
#pragma unroll 8
    for (int f = 0; f < 128; ++f) s += mhfull[f] * fr[f];
    uvec[idx] = s;
  }
}

// ------------------------- out2 = hidden@M2 - m*u + fc_b ; BN2 partials -------------------------
__global__ void k_out2(const float* __restrict__ hidden, const float* __restrict__ mvec,
                       const float* __restrict__ m2g, const float* __restrict__ uvec,
                       const float* __restrict__ fcb, float* __restrict__ out2,
                       float* __restrict__ bn2p) {
  extern __shared__ char smo[];
  float* m2l = (float*)smo;       // 16384
  float* hl = m2l + 16384;        // 4096
  float* ml = hl + 4096;          // 32
  float* red = ml + 32;           // 512
  int tid = threadIdx.x, blk = blockIdx.x, n0 = blk * 32;
  for (int idx = tid; idx < 16384; idx += 256) m2l[idx] = m2g[idx];
  for (int idx = tid; idx < 4096; idx += 256) hl[idx] = hidden[(size_t)n0 * 128 + idx];
  if (tid < 32) ml[tid] = mvec[n0 + tid];
  __syncthreads();
  int j = tid & 127, rg = tid >> 7;
  float uj = uvec[j], bj = fcb[j];
  float s1 = 0.f, s2 = 0.f;
  for (int q = 0; q < 16; ++q) {
    int nl = rg * 16 + q;
    float s = bj - ml[nl] * uj;
    const float* hr = hl + nl * 128;
#pragma unroll 8
    for (int k = 0; k < 128; ++k) s += hr[k] * m2l[k * 128 + j];
    out2[(size_t)(n0 + nl) * 128 + j] = s;
    s1 += s; s2 += s * s;
  }
  red[tid] = s1; red[256 + tid] = s2;
  __syncthreads();
  if (tid < 128) {
    bn2p[blk * 256 + tid] = red[tid] + red[128 + tid];
    bn2p[blk * 256 + 128 + tid] = red[256 + tid] + red[384 + tid];
  }
}

// ------------------------- BN2 stats -------------------------
__global__ void k_bn2(const float* __restrict__ bn2p, float* __restrict__ mu2,
                      float* __restrict__ rs2) {
  int j = threadIdx.x;  // 128
  float s = 0.f, q = 0.f;
  for (int b = 0; b < 256; ++b) {
    s += bn2p[b * 256 + j];
    q += bn2p[b * 256 + 128 + j];
  }
  float mu = s / 8192.f, var = q / 8192.f - mu * mu;
  mu2[j] = mu; rs2[j] = rsqrtf(var + 1e-5f);
}

// ------------------------- BN2 apply + leaky-relu + final GEMV -------------------------
__global__ void k_fin(const float* __restrict__ out2, const float* __restrict__ mu2,
                      const float* __restrict__ rs2, const float* __restrict__ g2,
                      const float* __restrict__ b2, const float* __restrict__ fcow,
                      const float* __restrict__ fcob, float* __restrict__ y) {
  int tid = threadIdx.x, lane = tid & 63, w = tid >> 6;
  int n = blockIdx.x * 4 + w;
  float s = 0.f;
#pragma unroll
  for (int h = 0; h < 2; ++h) {
    int j = lane + h * 64;
    float v = (out2[(size_t)n * 128 + j] - mu2[j]) * rs2[j] * g2[j] + b2[j];
    v = fmaxf(v, 0.01f * v);
    s += v * fcow[j];
  }
  for (int off = 32; off; off >>= 1) s += __shfl_down(s, off);
  if (!lane) y[n] = s + fcob[0];
}

// ------------------------- launch -------------------------
extern "C" void kernel_launch(void* const* d_in, const int* in_sizes, int n_in,
                              void* d_out, int out_size, void* d_ws, size_t ws_size,
                              hipStream_t stream) {
  const float* x    = (const float*)d_in[0];
  const float* wih0 = (const float*)d_in[1];
  const float* whh0 = (const float*)d_in[2];
  const float* bih0 = (const float*)d_in[3];
  const float* bhh0 = (const float*)d_in[4];
  const float* wih1 = (const float*)d_in[5];
  const float* whh1 = (const float*)d_in[6];
  const float* bih1 = (const float*)d_in[7];
  const float* bhh1 = (const float*)d_in[8];
  const float* g1   = (const float*)d_in[9];
  const float* b1   = (const float*)d_in[10];
  const float* fcw  = (const float*)d_in[11];
  const float* fcb  = (const float*)d_in[12];
  const float* g2   = (const float*)d_in[13];
  const float* b2   = (const float*)d_in[14];
  const float* fcow = (const float*)d_in[15];
  const float* fcob = (const float*)d_in[16];

  char* ws = (char*)d_ws;
  u16*   whh0b  = (u16*)(ws + 0);
  u16*   wih1b  = (u16*)(ws + 98304);
  u16*   whh1b  = (u16*)(ws + 196608);
  float* hraw   = (float*)(ws + 294912);
  float* hidden = (float*)(ws + 4489216);
  float* mvec   = (float*)(ws + 8683520);
  float* mu1    = (float*)(ws + 8716288);
  float* rs1    = (float*)(ws + 8716800);
  float* gpart  = (float*)(ws + 8717312);
  float* mhpart = (float*)(ws + 17105920);
  float* m2     = (float*)(ws + 17171456);
  float* uvec   = (float*)(ws + 17236992);
  float* out2   = (float*)(ws + 17237504);
  float* bn2p   = (float*)(ws + 21431808);  // reused: bn1 partials live here first
  float* mu2    = (float*)(ws + 21693952);
  float* rs2    = (float*)(ws + 21694464);
  float* gfull  = (float*)(ws + 21694976);
  float* mhfull = (float*)(ws + 21760512);

  (void)hipFuncSetAttribute((const void*)k_gru,
                            hipFuncAttributeMaxDynamicSharedMemorySize, GRU_LDS);
  (void)hipFuncSetAttribute((const void*)k_out2,
                            hipFuncAttributeMaxDynamicSharedMemorySize, 84096);

  k_prep<<<192, 256, 0, stream>>>(whh0, wih1, whh1, whh0b, wih1b, whh1b);
  k_gru<<<256, 512, GRU_LDS, stream>>>(x, wih0, bih0, bhh0, whh0b, wih1b, whh1b,
                                       bih1, bhh1, hraw);
  k_bn1p<<<128, 256, 0, stream>>>(hraw, bn2p);
  k_bn1r<<<1, 128, 0, stream>>>(bn2p, mu1, rs1);
  k_attp<<<128, 256, 0, stream>>>(hraw, mu1, rs1, g1, b1, hidden, mvec, gpart, mhpart);
  k_attfa<<<64, 256, 0, stream>>>(gpart, mhpart, gfull, mhfull);
  k_attfb<<<128, 128, 0, stream>>>(gfull, mhfull, fcw, m2, uvec);
  k_out2<<<256, 256, 84096, stream>>>(hidden, mvec, m2, uvec, fcb, out2, bn2p);
  k_bn2<<<1, 128, 0, stream>>>(bn2p, mu2, rs2);
  k_fin<<<2048, 256, 0, stream>>>(out2, mu2, rs2, g2, b2, fcow, fcob, (float*)d_out);
}

// Round 3
// 310.438 us; speedup vs baseline: 2.1801x; 1.2254x over previous
//
#include <hip/hip_runtime.h>

typedef unsigned short u16;
typedef short bf16x8 __attribute__((ext_vector_type(8)));
typedef float f32x4 __attribute__((ext_vector_type(4)));

#define NBATCH 8192

__device__ __forceinline__ f32x4 mfma16(bf16x8 a, bf16x8 b, f32x4 c) {
  return __builtin_amdgcn_mfma_f32_16x16x32_bf16(a, b, c, 0, 0, 0);
}
__device__ __forceinline__ u16 f2bf(float f) {
  unsigned int u = __float_as_uint(f);
  return (u16)((u + 0x7FFFu + ((u >> 16) & 1u)) >> 16);
}
__device__ __forceinline__ float bf2f(u16 h) {
  return __uint_as_float(((unsigned int)h) << 16);
}
__device__ __forceinline__ float sigm(float x) {
  return __builtin_amdgcn_rcpf(1.f + __builtin_amdgcn_exp2f(-1.44269504f * x));
}
__device__ __forceinline__ float tanh_(float x) {
  float t = __builtin_amdgcn_exp2f(2.88539008f * x);
  return 1.f - 2.f * __builtin_amdgcn_rcpf(t + 1.f);
}
__device__ __forceinline__ bf16x8 pack8(const float* p) {
  float4 a = *(const float4*)p, b = *(const float4*)(p + 4);
  bf16x8 r;
  r[0] = (short)f2bf(a.x); r[1] = (short)f2bf(a.y);
  r[2] = (short)f2bf(a.z); r[3] = (short)f2bf(a.w);
  r[4] = (short)f2bf(b.x); r[5] = (short)f2bf(b.y);
  r[6] = (short)f2bf(b.z); r[7] = (short)f2bf(b.w);
  return r;
}

// ------------------------- fused 2-layer GRU recurrence -------------------------
// 256 blocks x 512 threads (8 waves). 32 samples/block, 64 steps, both layers.
// 1 barrier/step: double-buffered bf16 h0/h1/x in LDS; fp32 state in registers.
// LDS: W_hh0 bf16 swizzled 96K | h0b x2 16K | h1b x2 16K | xbuf x2 4K = 132K
#define WHH0_OFF 0
#define H0B_OFF  98304
#define H1B_OFF  114688
#define XB_OFF   131072
#define GRU_LDS  135168

// one GRU step. RD/WR are 0/1 buffer selectors (literal constants at expansion).
#define GRU_STEP(RD, WR, T)                                                     \
  {                                                                             \
    if (xact && (T) < 63) {                                                     \
      u16 xh = f2bf(xv);                                                        \
      u16 xl = f2bf(xv - bf2f(xh));                                             \
      char* xw = sm + XB_OFF + (WR)*2048 + xm*64 + xd*2;                        \
      *(u16*)xw = xh; *(u16*)(xw + 16) = xl; *(u16*)(xw + 32) = xh;             \
      if ((T) < 62) xv = gx[(T) + 2];                                           \
    }                                                                           \
    f32x4 rz0[2][2], hn0[2], in0[2];                                            \
    _Pragma("unroll") for (int mt = 0; mt < 2; ++mt) {                          \
      rz0[mt][0] = (f32x4){brz0r, brz0r, brz0r, brz0r};                         \
      rz0[mt][1] = (f32x4){brz0z, brz0z, brz0z, brz0z};                         \
      hn0[mt] = (f32x4){bhn0, bhn0, bhn0, bhn0};                                \
      in0[mt] = (f32x4){bin0, bin0, bin0, bin0};                                \
    }                                                                           \
    _Pragma("unroll") for (int ki = 0; ki < 4; ++ki) {                          \
      bf16x8 a0 = *(bf16x8*)(sm + H0B_OFF + (RD)*8192 + arow0 + ad[ki]);        \
      bf16x8 a1 = *(bf16x8*)(sm + H0B_OFF + (RD)*8192 + arow1 + ad[ki]);        \
      bf16x8 b0 = *(bf16x8*)(sm + brow0 + ad[ki]);                              \
      bf16x8 b1 = *(bf16x8*)(sm + brow1 + ad[ki]);                              \
      bf16x8 b2 = *(bf16x8*)(sm + brow2 + ad[ki]);                              \
      rz0[0][0] = mfma16(a0, b0, rz0[0][0]);                                    \
      rz0[0][1] = mfma16(a0, b1, rz0[0][1]);                                    \
      hn0[0]    = mfma16(a0, b2, hn0[0]);                                       \
      rz0[1][0] = mfma16(a1, b0, rz0[1][0]);                                    \
      rz0[1][1] = mfma16(a1, b1, rz0[1][1]);                                    \
      hn0[1]    = mfma16(a1, b2, hn0[1]);                                       \
    }                                                                           \
    {                                                                           \
      bf16x8 ax0 = *(bf16x8*)(sm + XB_OFF + (RD)*2048 + xr0);                   \
      bf16x8 ax1 = *(bf16x8*)(sm + XB_OFF + (RD)*2048 + xr1);                   \
      rz0[0][0] = mfma16(ax0, wf0a, rz0[0][0]);                                 \
      rz0[0][1] = mfma16(ax0, wf0b, rz0[0][1]);                                 \
      in0[0]    = mfma16(ax0, wf0c, in0[0]);                                    \
      rz0[1][0] = mfma16(ax1, wf0a, rz0[1][0]);                                 \
      rz0[1][1] = mfma16(ax1, wf0b, rz0[1][1]);                                 \
      in0[1]    = mfma16(ax1, wf0c, in0[1]);                                    \
    }                                                                           \
    _Pragma("unroll") for (int mt = 0; mt < 2; ++mt)                            \
    _Pragma("unroll") for (int r = 0; r < 4; ++r) {                             \
      int s = mt*4 + r;                                                         \
      float rr = sigm(rz0[mt][0][r]);                                           \
      float zz = sigm(rz0[mt][1][r]);                                           \
      float nn = tanh_(__builtin_fmaf(rr, hn0[mt][r], in0[mt][r]));             \
      float h = h0s[s]; h = __builtin_fmaf(zz, h - nn, nn); h0s[s] = h;         \
      *(u16*)(sm + H0B_OFF + (WR)*8192 + st[s]) = f2bf(h);                      \
    }                                                                           \
    __syncthreads();                                                            \
    f32x4 rz1[2][2], hn1[2], in1[2];                                            \
    _Pragma("unroll") for (int mt = 0; mt < 2; ++mt) {                          \
      rz1[mt][0] = (f32x4){brz1r, brz1r, brz1r, brz1r};                         \
      rz1[mt][1] = (f32x4){brz1z, brz1z, brz1z, brz1z};                         \
      hn1[mt] = (f32x4){bhn1, bhn1, bhn1, bhn1};                                \
      in1[mt] = (f32x4){bin1, bin1, bin1, bin1};                                \
    }                                                                           \
    _Pragma("unroll") for (int ki = 0; ki < 4; ++ki) {                          \
      bf16x8 p0 = *(bf16x8*)(sm + H0B_OFF + (WR)*8192 + arow0 + ad[ki]);        \
      bf16x8 p1 = *(bf16x8*)(sm + H0B_OFF + (WR)*8192 + arow1 + ad[ki]);        \
      bf16x8 q0 = *(bf16x8*)(sm + H1B_OFF + (RD)*8192 + arow0 + ad[ki]);        \
      bf16x8 q1 = *(bf16x8*)(sm + H1B_OFF + (RD)*8192 + arow1 + ad[ki]);        \
      rz1[0][0] = mfma16(p0, wih1f[0][ki], rz1[0][0]);                          \
      rz1[0][0] = mfma16(q0, whh1f[0][ki], rz1[0][0]);                          \
      rz1[0][1] = mfma16(p0, wih1f[1][ki], rz1[0][1]);                          \
      rz1[0][1] = mfma16(q0, whh1f[1][ki], rz1[0][1]);                          \
      in1[0]    = mfma16(p0, wih1f[2][ki], in1[0]);                             \
      hn1[0]    = mfma16(q0, whh1f[2][ki], hn1[0]);                             \
      rz1[1][0] = mfma16(p1, wih1f[0][ki], rz1[1][0]);                          \
      rz1[1][0] = mfma16(q1, whh1f[0][ki], rz1[1][0]);                          \
      rz1[1][1] = mfma16(p1, wih1f[1][ki], rz1[1][1]);                          \
      rz1[1][1] = mfma16(q1, whh1f[1][ki], rz1[1][1]);                          \
      in1[1]    = mfma16(p1, wih1f[2][ki], in1[1]);                             \
      hn1[1]    = mfma16(q1, whh1f[2][ki], hn1[1]);                             \
    }                                                                           \
    _Pragma("unroll") for (int mt = 0; mt < 2; ++mt)                            \
    _Pragma("unroll") for (int r = 0; r < 4; ++r) {                             \
      int s = mt*4 + r;                                                         \
      float rr = sigm(rz1[mt][0][r]);                                           \
      float zz = sigm(rz1[mt][1][r]);                                           \
      float nn = tanh_(__builtin_fmaf(rr, hn1[mt][r], in1[mt][r]));             \
      float h = h1s[s]; h = __builtin_fmaf(zz, h - nn, nn); h1s[s] = h;         \
      *(u16*)(sm + H1B_OFF + (WR)*8192 + st[s]) = f2bf(h);                      \
    }                                                                           \
  }

__global__ __launch_bounds__(512, 2)
void k_gru(const float* __restrict__ x,
           const float* __restrict__ wih0, const float* __restrict__ whh0,
           const float* __restrict__ bih0, const float* __restrict__ bhh0,
           const float* __restrict__ wih1, const float* __restrict__ whh1,
           const float* __restrict__ bih1, const float* __restrict__ bhh1,
           float* __restrict__ hraw) {
  extern __shared__ char sm[];
  const int tid = threadIdx.x;
  const int wid = tid >> 6;
  const int lane = tid & 63;
  const int lq = lane >> 4;
  const int ul = lane & 15;
  const int u  = wid * 16 + ul;
  const int n0 = blockIdx.x * 32;
  const int sx = (ul & 7) << 4;

  // zero h0b/h1b/xbuf (36864 B)
  for (int idx = tid; idx < 9216; idx += 512)
    *(float*)(sm + H0B_OFF + idx * 4) = 0.f;
  // stage W_hh0 fp32->bf16 into LDS, swizzled
  for (int idx = tid; idx < 12288; idx += 512) {
    int g = idx >> 5, c4 = (idx & 31) * 4;
    float4 v = *(const float4*)(whh0 + g * 128 + c4);
    unsigned int p0 = (unsigned int)f2bf(v.x) | ((unsigned int)f2bf(v.y) << 16);
    unsigned int p1 = (unsigned int)f2bf(v.z) | ((unsigned int)f2bf(v.w) << 16);
    unsigned int* dst = (unsigned int*)(sm + WHH0_OFF + g * 256 + ((c4 * 2) ^ ((g & 7) << 4)));
    dst[0] = p0; dst[1] = p1;
  }

  // register-resident B-fragments for W_ih1, W_hh1 (fp32 global -> bf16)
  bf16x8 wih1f[3][4], whh1f[3][4];
#pragma unroll
  for (int i = 0; i < 3; ++i) {
    int g = u + 128 * i;
#pragma unroll
    for (int ki = 0; ki < 4; ++ki) {
      wih1f[i][ki] = pack8(wih1 + g * 128 + ki * 32 + lq * 8);
      whh1f[i][ki] = pack8(whh1 + g * 128 + ki * 32 + lq * 8);
    }
  }
  // W_ih0 fragments for the exact hi/lo gi0 MFMA:
  // k0-5: whi (x-hi), k8-13: whi (x-lo), k16-21: wlo (x-hi), rest 0.
  bf16x8 wf0a, wf0b, wf0c;
  {
    u16 t0[8] = {0,0,0,0,0,0,0,0}, t1[8] = {0,0,0,0,0,0,0,0}, t2[8] = {0,0,0,0,0,0,0,0};
    u16* ts[3] = {t0, t1, t2};
#pragma unroll
    for (int i = 0; i < 3; ++i) {
      int g = u + 128 * i;
      if (lq < 2) {
        for (int d = 0; d < 6; ++d) ts[i][d] = f2bf(wih0[g * 6 + d]);
      } else if (lq == 2) {
        for (int d = 0; d < 6; ++d) {
          float w = wih0[g * 6 + d];
          u16 h = f2bf(w);
          ts[i][d] = f2bf(w - bf2f(h));
        }
      }
    }
    wf0a = *(bf16x8*)t0; wf0b = *(bf16x8*)t1; wf0c = *(bf16x8*)t2;
  }
  // biases (r,z folded as sums; n kept separate for the r*hn structure)
  const float brz0r = bih0[u] + bhh0[u];
  const float brz0z = bih0[u + 128] + bhh0[u + 128];
  const float bin0 = bih0[u + 256], bhn0 = bhh0[u + 256];
  const float brz1r = bih1[u] + bhh1[u];
  const float brz1z = bih1[u + 128] + bhh1[u + 128];
  const float bin1 = bih1[u + 256], bhn1 = bhh1[u + 256];

  // per-lane precomputed offsets
  int ad[4];
#pragma unroll
  for (int ki = 0; ki < 4; ++ki) ad[ki] = (ki * 64 + lq * 16) ^ sx;
  const int arow0 = ul * 256, arow1 = arow0 + 4096;
  const int xr0 = ul * 64 + lq * 16, xr1 = xr0 + 1024;
  const int brow0 = WHH0_OFF + u * 256;
  const int brow1 = WHH0_OFF + (u + 128) * 256;
  const int brow2 = WHH0_OFF + (u + 256) * 256;
  int st[8];
#pragma unroll
  for (int mt = 0; mt < 2; ++mt)
#pragma unroll
    for (int r = 0; r < 4; ++r) {
      int m = mt * 16 + lq * 4 + r;
      st[mt * 4 + r] = m * 256 + ((u * 2) ^ ((m & 7) << 4));
    }

  // fp32 recurrent state in registers
  float h0s[8], h1s[8];
#pragma unroll
  for (int s = 0; s < 8; ++s) { h0s[s] = 0.f; h1s[s] = 0.f; }

  // x prefetch: 192 threads own one (sample, feature) pair
  const int xm = tid / 6, xd = tid - 6 * xm;
  const bool xact = tid < 192;
  const float* gx = x + (size_t)(n0 + xm) * 384 + xd * 64;

  __syncthreads();  // zeros/staging visible before x(0) stage

  float xv = 0.f;
  if (xact) {
    float x0 = gx[0];
    u16 h = f2bf(x0);
    u16 l = f2bf(x0 - bf2f(h));
    char* p = sm + XB_OFF + xm * 64 + xd * 2;
    *(u16*)p = h; *(u16*)(p + 16) = l; *(u16*)(p + 32) = h;
    xv = gx[1];
  }
  __syncthreads();  // x(0) visible

  for (int t = 0; t < 64; t += 2) {
    GRU_STEP(0, 1, t)
    GRU_STEP(1, 0, t + 1)
  }

  // write final h1 from registers
#pragma unroll
  for (int mt = 0; mt < 2; ++mt)
#pragma unroll
    for (int r = 0; r < 4; ++r) {
      int m = mt * 16 + lq * 4 + r;
      hraw[(size_t)(n0 + m) * 128 + u] = h1s[mt * 4 + r];
    }
}

// ------------------------- BN1 partials (coalesced) -------------------------
__global__ void k_bn1p(const float* __restrict__ hraw, float* __restrict__ p) {
  __shared__ float s0[256], s1[256];
  int tid = threadIdx.x, b = blockIdx.x;
  int f = tid & 127, r = tid >> 7;
  float s = 0.f, q = 0.f;
  for (int n = b * 64 + r; n < b * 64 + 64; n += 2) {
    float v = hraw[(size_t)n * 128 + f];
    s += v; q += v * v;
  }
  s0[tid] = s; s1[tid] = q;
  __syncthreads();
  if (tid < 128) {
    p[b * 256 + tid] = s0[tid] + s0[tid + 128];
    p[b * 256 + 128 + tid] = s1[tid] + s1[tid + 128];
  }
}

__global__ void k_bn1r(const float* __restrict__ p, float* __restrict__ mu1,
                       float* __restrict__ rs1) {
  int f = threadIdx.x;
  float s = 0.f, q = 0.f;
  for (int b = 0; b < 128; ++b) { s += p[b * 256 + f]; q += p[b * 256 + 128 + f]; }
  float mu = s / 8192.f, var = q / 8192.f - mu * mu;
  mu1[f] = mu; rs1[f] = rsqrtf(var + 1e-5f);
}

// ------------------------- BN1 apply + row means + Gram/mh partials -------------------------
__global__ void k_attp(const float* __restrict__ hraw, const float* __restrict__ mu1,
                       const float* __restrict__ rs1, const float* __restrict__ g1,
                       const float* __restrict__ b1, float* __restrict__ hidden,
                       float* __restrict__ mvec, float* __restrict__ gpart,
                       float* __restrict__ mhpart) {
  __shared__ float hid[64][128];
  __shared__ float mld[64];
  int tid = threadIdx.x, blk = blockIdx.x, n0 = blk * 64;
  for (int idx = tid; idx < 64 * 128; idx += 256) {
    int n = idx >> 7, f = idx & 127;
    float v = (hraw[(size_t)(n0 + n) * 128 + f] - mu1[f]) * rs1[f] * g1[f] + b1[f];
    hid[n][f] = v;
    hidden[(size_t)(n0 + n) * 128 + f] = v;
  }
  __syncthreads();
  if (tid < 64) {
    float s = 0.f;
    for (int f = 0; f < 128; ++f) s += hid[tid][f];
    s *= (1.f / 128.f);
    mld[tid] = s; mvec[n0 + tid] = s;
  }
  __syncthreads();
  int i = tid >> 1, j0 = (tid & 1) * 64;
  float acc[64];
#pragma unroll
  for (int j = 0; j < 64; ++j) acc[j] = 0.f;
  for (int n = 0; n < 64; ++n) {
    float a = hid[n][i];
#pragma unroll
    for (int j = 0; j < 64; ++j) acc[j] += a * hid[n][j0 + j];
  }
#pragma unroll
  for (int j = 0; j < 64; ++j) gpart[(size_t)blk * 16384 + i * 128 + j0 + j] = acc[j];
  if (tid < 128) {
    float s = 0.f;
    for (int n = 0; n < 64; ++n) s += mld[n] * hid[n][tid];
    mhpart[blk * 128 + tid] = s;
  }
}

// ------------------------- reduce Gram/mh partials -------------------------
__global__ void k_attfa(const float* __restrict__ gpart, const float* __restrict__ mhpart,
                        float* __restrict__ gfull, float* __restrict__ mhfull) {
  int idx = blockIdx.x * 256 + threadIdx.x;
  float s = 0.f;
  for (int b = 0; b < 128; ++b) s += gpart[(size_t)b * 16384 + idx];
  gfull[idx] = s;
  if (blockIdx.x == 0 && threadIdx.x < 128) {
    float t = 0.f;
    for (int b = 0; b < 128; ++b) t += mhpart[b * 128 + threadIdx.x];
    mhfull[threadIdx.x] = t;
  }
}

// ------------------------- M2 = (G/H) @ fc_w^T ; u = mh @ fc_w^T -------------------------
__global__ void k_attfb(const float* __restrict__ gfull, const float* __restrict__ mhfull,
                        const float* __restrict__ fcw, float* __restrict__ m2,
                        float* __restrict__ uvec) {
  int idx = blockIdx.x * 128 + threadIdx.x;
  int k = idx >> 7, j = idx & 127;
  const float4* ga = (const float4*)(gfull + k * 128);
  const float4* fb = (const float4*)(fcw + j * 128);
  float a0 = 0.f, a1 = 0.f, a2 = 0.f, a3 = 0.f;
#pragma unroll 8
  for (int f = 0; f < 32; ++f) {
    float4 a = ga[f], b = fb[f];
    a0 += a.x * b.x; a1 += a.y * b.y; a2 += a.z * b.z; a3 += a.w * b.w;
  }
  m2[idx] = (a0 + a1 + a2 + a3) * (1.f / 128.f);
  if (idx < 128) {
    float s = 0.f;
    const float* fr = fcw + idx * 128;
#pragma unroll 8
    for (int f = 0; f < 128; ++f) s += mhfull[f] * fr[f];
    uvec[idx] = s;
  }
}

// ------------------------- out2 = hidden@M2 - m*u + fc_b ; BN2 partials -------------------------
__global__ void k_out2(const float* __restrict__ hidden, const float* __restrict__ mvec,
                       const float* __restrict__ m2g, const float* __restrict__ uvec,
                       const float* __restrict__ fcb, float* __restrict__ out2,
                       float* __restrict__ bn2p) {
  extern __shared__ char smo[];
  float* m2l = (float*)smo;
  float* hl = m2l + 16384;
  float* ml = hl + 4096;
  float* red = ml + 32;
  int tid = threadIdx.x, blk = blockIdx.x, n0 = blk * 32;
  for (int idx = tid; idx < 16384; idx += 256) m2l[idx] = m2g[idx];
  for (int idx = tid; idx < 4096; idx += 256) hl[idx] = hidden[(size_t)n0 * 128 + idx];
  if (tid < 32) ml[tid] = mvec[n0 + tid];
  __syncthreads();
  int j = tid & 127, rg = tid >> 7;
  float uj = uvec[j], bj = fcb[j];
  float s1 = 0.f, s2 = 0.f;
  for (int q = 0; q < 16; ++q) {
    int nl = rg * 16 + q;
    float s = bj - ml[nl] * uj;
    const float* hr = hl + nl * 128;
#pragma unroll 8
    for (int k = 0; k < 128; ++k) s += hr[k] * m2l[k * 128 + j];
    out2[(size_t)(n0 + nl) * 128 + j] = s;
    s1 += s; s2 += s * s;
  }
  red[tid] = s1; red[256 + tid] = s2;
  __syncthreads();
  if (tid < 128) {
    bn2p[blk * 256 + tid] = red[tid] + red[128 + tid];
    bn2p[blk * 256 + 128 + tid] = red[256 + tid] + red[384 + tid];
  }
}

// ------------------------- BN2 stats -------------------------
__global__ void k_bn2(const float* __restrict__ bn2p, float* __restrict__ mu2,
                      float* __restrict__ rs2) {
  int j = threadIdx.x;
  float s = 0.f, q = 0.f;
  for (int b = 0; b < 256; ++b) {
    s += bn2p[b * 256 + j];
    q += bn2p[b * 256 + 128 + j];
  }
  float mu = s / 8192.f, var = q / 8192.f - mu * mu;
  mu2[j] = mu; rs2[j] = rsqrtf(var + 1e-5f);
}

// ------------------------- BN2 apply + leaky-relu + final GEMV -------------------------
__global__ void k_fin(const float* __restrict__ out2, const float* __restrict__ mu2,
                      const float* __restrict__ rs2, const float* __restrict__ g2,
                      const float* __restrict__ b2, const float* __restrict__ fcow,
                      const float* __restrict__ fcob, float* __restrict__ y) {
  int tid = threadIdx.x, lane = tid & 63, w = tid >> 6;
  int n = blockIdx.x * 4 + w;
  float s = 0.f;
#pragma unroll
  for (int h = 0; h < 2; ++h) {
    int j = lane + h * 64;
    float v = (out2[(size_t)n * 128 + j] - mu2[j]) * rs2[j] * g2[j] + b2[j];
    v = fmaxf(v, 0.01f * v);
    s += v * fcow[j];
  }
  for (int off = 32; off; off >>= 1) s += __shfl_down(s, off);
  if (!lane) y[n] = s + fcob[0];
}

// ------------------------- launch -------------------------
extern "C" void kernel_launch(void* const* d_in, const int* in_sizes, int n_in,
                              void* d_out, int out_size, void* d_ws, size_t ws_size,
                              hipStream_t stream) {
  const float* x    = (const float*)d_in[0];
  const float* wih0 = (const float*)d_in[1];
  const float* whh0 = (const float*)d_in[2];
  const float* bih0 = (const float*)d_in[3];
  const float* bhh0 = (const float*)d_in[4];
  const float* wih1 = (const float*)d_in[5];
  const float* whh1 = (const float*)d_in[6];
  const float* bih1 = (const float*)d_in[7];
  const float* bhh1 = (const float*)d_in[8];
  const float* g1   = (const float*)d_in[9];
  const float* b1   = (const float*)d_in[10];
  const float* fcw  = (const float*)d_in[11];
  const float* fcb  = (const float*)d_in[12];
  const float* g2   = (const float*)d_in[13];
  const float* b2   = (const float*)d_in[14];
  const float* fcow = (const float*)d_in[15];
  const float* fcob = (const float*)d_in[16];

  char* ws = (char*)d_ws;
  float* hraw   = (float*)(ws + 0);
  float* hidden = (float*)(ws + 4194304);
  float* mvec   = (float*)(ws + 8388608);
  float* mu1    = (float*)(ws + 8421376);
  float* rs1    = (float*)(ws + 8421888);
  float* gpart  = (float*)(ws + 8422400);
  float* mhpart = (float*)(ws + 16811008);
  float* m2     = (float*)(ws + 16876544);
  float* uvec   = (float*)(ws + 16942080);
  float* out2   = (float*)(ws + 16942592);
  float* bn2p   = (float*)(ws + 21136896);  // reused: bn1 partials live here first
  float* mu2    = (float*)(ws + 21399040);
  float* rs2    = (float*)(ws + 21399552);
  float* gfull  = (float*)(ws + 21400064);
  float* mhfull = (float*)(ws + 21465600);

  (void)hipFuncSetAttribute((const void*)k_gru,
                            hipFuncAttributeMaxDynamicSharedMemorySize, GRU_LDS);
  (void)hipFuncSetAttribute((const void*)k_out2,
                            hipFuncAttributeMaxDynamicSharedMemorySize, 84096);

  k_gru<<<256, 512, GRU_LDS, stream>>>(x, wih0, whh0, bih0, bhh0, wih1, whh1,
                                       bih1, bhh1, hraw);
  k_bn1p<<<128, 256, 0, stream>>>(hraw, bn2p);
  k_bn1r<<<1, 128, 0, stream>>>(bn2p, mu1, rs1);
  k_attp<<<128, 256, 0, stream>>>(hraw, mu1, rs1, g1, b1, hidden, mvec, gpart, mhpart);
  k_attfa<<<64, 256, 0, stream>>>(gpart, mhpart, gfull, mhfull);
  k_attfb<<<128, 128, 0, stream>>>(gfull, mhfull, fcw, m2, uvec);
  k_out2<<<256, 256, 84096, stream>>>(hidden, mvec, m2, uvec, fcb, out2, bn2p);
  k_bn2<<<1, 128, 0, stream>>>(bn2p, mu2, rs2);
  k_fin<<<2048, 256, 0, stream>>>(out2, mu2, rs2, g2, b2, fcow, fcob, (float*)d_out);
}